// Round 2
// baseline (253.365 us; speedup 1.0000x reference)
//
#include <hip/hip_runtime.h>
#include <stdint.h>

// MomentumLIF: x[N,T,D] f32 -> spikes[N,T,D] f32 (0/1)
//   v_t = mom*v + x_t - lamb*u ; u_t = 0.5*u + v_t ; s = (u>=1); u *= (1-s)
//
// R10: single fused kernel, phase-split INSIDE the kernel.
//   R1 post-mortem: interleaved nt-stores sat in the in-order vmcnt queue
//   between pipelined loads -> every load wait also waited on a store ack;
//   VALUBusy 6%, 2.3 TB/s. Fix: no store is ever issued while the load
//   ring is live.
//   - Phase 1 (pure read): 16-deep float4 ring over t, recurrence packs
//     spikes into 2x32-bit words per chain (4 chains/thread = one float4
//     column). Only loads occupy vmcnt.
//   - Phase 2 (pure write): 64 unrolled bit-expand -> nontemporal float4
//     stores. Stores never gate a wait.
//   No ws round-trip, no second dispatch, no graph gap.
//   Arithmetic order identical to the absmax==0 kernels (contract off).

#define N_ 64
#define T_ 64
#define D_ 8192
#define PF 16   // load pipeline depth (float4 tiles in flight per thread)
#define CPT 4   // chains per thread (one float4 of d)

typedef __attribute__((ext_vector_type(4))) float f32x4;

__global__ __launch_bounds__(256) void lif_fused(
    const float* __restrict__ x,
    const float* __restrict__ momp,
    const float* __restrict__ lambp,
    float* __restrict__ out)
{
    // Match numpy f32 semantics exactly: no FMA contraction anywhere.
#pragma clang fp contract(off)
    const float mom   = momp[0];
    const float lamb  = lambp[0];
    const float decay = 0.5f;   // 1 - 1/TAU, exact

    const int g  = blockIdx.x * blockDim.x + threadIdx.x;  // 0 .. N*D/4 - 1
    const int n  = g >> 11;                  // g / (D_/CPT)
    const int dq = g & 2047;                 // float4 index within a row
    const size_t base = (size_t)n * (size_t)(T_ * D_) + ((size_t)dq << 2);

    const f32x4* __restrict__ xv = reinterpret_cast<const f32x4*>(x + base);
    f32x4* __restrict__ ov       = reinterpret_cast<f32x4*>(out + base);
    const int RS = D_ / 4;                   // row stride in f32x4 units

    // ---------------- Phase 1: pure-read pipeline + recurrence ----------
    f32x4 buf[PF];
#pragma unroll
    for (int i = 0; i < PF; ++i) buf[i] = xv[(size_t)i * RS];

    float u[CPT] = {0.f, 0.f, 0.f, 0.f};
    float v[CPT] = {0.f, 0.f, 0.f, 0.f};
    uint32_t blo[CPT] = {0u, 0u, 0u, 0u};    // spike bits t<32
    uint32_t bhi[CPT] = {0u, 0u, 0u, 0u};    // spike bits t>=32

#pragma unroll
    for (int t = 0; t < T_ - PF; ++t) {
        const f32x4 xt = buf[t & (PF - 1)];
        buf[t & (PF - 1)] = xv[(size_t)(t + PF) * RS];
#pragma unroll
        for (int c = 0; c < CPT; ++c) {
            const float t1 = mom * v[c];     // separately rounded, matches numpy
            const float t2 = lamb * u[c];
            v[c] = (t1 + xt[c]) - t2;
            u[c] = decay * u[c] + v[c];
            const bool sp = (u[c] >= 1.0f);
            if (t < 32) blo[c] |= ((uint32_t)sp) << t;
            else        bhi[c] |= ((uint32_t)sp) << (t - 32);
            u[c] = sp ? 0.0f : u[c];         // u*(1-s) is exactly this select
        }
    }

#pragma unroll
    for (int t = T_ - PF; t < T_; ++t) {     // drain the ring, no more loads
        const f32x4 xt = buf[t & (PF - 1)];
#pragma unroll
        for (int c = 0; c < CPT; ++c) {
            const float t1 = mom * v[c];
            const float t2 = lamb * u[c];
            v[c] = (t1 + xt[c]) - t2;
            u[c] = decay * u[c] + v[c];
            const bool sp = (u[c] >= 1.0f);
            if (t < 32) blo[c] |= ((uint32_t)sp) << t;
            else        bhi[c] |= ((uint32_t)sp) << (t - 32);
            u[c] = sp ? 0.0f : u[c];
        }
    }

    // ---------------- Phase 2: pure-write burst -------------------------
#pragma unroll
    for (int t = 0; t < T_; ++t) {
        f32x4 o;
#pragma unroll
        for (int c = 0; c < CPT; ++c) {
            const uint32_t w = (t < 32) ? blo[c] : bhi[c];
            o[c] = ((w >> (t & 31)) & 1u) ? 1.0f : 0.0f;
        }
        __builtin_nontemporal_store(o, ov + (size_t)t * RS);
    }
}

extern "C" void kernel_launch(void* const* d_in, const int* in_sizes, int n_in,
                              void* d_out, int out_size, void* d_ws, size_t ws_size,
                              hipStream_t stream) {
    const float* x    = (const float*)d_in[0];
    const float* momp = (const float*)d_in[1];
    const float* lamb = (const float*)d_in[2];
    float* out = (float*)d_out;

    dim3 block(256);
    dim3 grid((N_ * D_ / CPT) / 256);   // 512 blocks, one thread per 4 chains
    hipLaunchKernelGGL(lif_fused, grid, block, 0, stream, x, momp, lamb, out);
}

// Round 3
// 248.911 us; speedup vs baseline: 1.0179x; 1.0179x over previous
//
#include <hip/hip_runtime.h>
#include <stdint.h>

// MomentumLIF: x[N,T,D] f32 -> spikes[N,T,D] f32 (0/1)
//   v_t = mom*v + x_t - lamb*u ; u_t = 0.5*u + v_t ; s = (u>=1); u *= (1-s)
//
// R11 = R10's in-kernel phase split + R0's asm-enforced load pipeline.
//   R2 post-mortem: VGPR=40 proved the compiler collapsed the source-level
//   16-deep ring to ~2 tiles in flight (it sinks loads to their uses).
//   Fix: the ring is built from inline-asm global_load_dwordx4 + explicit
//   s_waitcnt vmcnt(7) ties -- invisible to the compiler's waitcnt pass,
//   impossible to collapse (asm volatile order is preserved).
//   - Phase 1 (pure read): 8-deep float4 asm ring over t; recurrence packs
//     spikes into 2x32-bit words per chain (4 chains/thread). Only loads
//     occupy the vmcnt queue -> no store-ack coupling (R1's failure).
//   - Phase 2 (pure write): 64 unrolled bit-expand -> nontemporal float4
//     stores, fully contiguous 1 KB/wave/instr.
//   Arithmetic order identical to the absmax==0 kernels (contract off).

#define N_ 64
#define T_ 64
#define D_ 8192
#define PF 8    // asm load ring depth (float4 tiles in flight per thread)
#define CPT 4   // chains per thread (one float4 of d)

typedef __attribute__((ext_vector_type(4))) float f32x4;

__global__ __launch_bounds__(256) void lif_fused(
    const float* __restrict__ x,
    const float* __restrict__ momp,
    const float* __restrict__ lambp,
    float* __restrict__ out)
{
    // Match numpy f32 semantics exactly: no FMA contraction anywhere.
#pragma clang fp contract(off)
    float mom  = momp[0];
    float lamb = lambp[0];
    const float decay = 0.5f;   // 1 - 1/TAU, exact

    // Pin scalars to SGPRs so our vmcnt arithmetic sees only our own loads.
    asm volatile("" : "+s"(mom), "+s"(lamb));

    const int g  = blockIdx.x * blockDim.x + threadIdx.x;  // 0 .. N*D/4 - 1
    const int n  = g >> 11;                  // g / (D_/CPT)
    const int dq = g & 2047;                 // float4 index within a row
    const size_t base = (size_t)n * (size_t)(T_ * D_) + ((size_t)dq << 2);

    const f32x4* __restrict__ xv = reinterpret_cast<const f32x4*>(x + base);
    f32x4* __restrict__ ov       = reinterpret_cast<f32x4*>(out + base);
    const int RS = D_ / 4;                   // row stride in f32x4 units

    asm volatile("s_waitcnt vmcnt(0)" ::: "memory");

    // ---------------- Phase 1: asm read ring + recurrence ----------------
    f32x4 xs[PF];
#pragma unroll
    for (int i = 0; i < PF; ++i) {
        const f32x4* a = xv + (size_t)i * RS;
        asm volatile("global_load_dwordx4 %0, %1, off" : "=v"(xs[i]) : "v"(a));
    }

    float u[CPT] = {0.f, 0.f, 0.f, 0.f};
    float v[CPT] = {0.f, 0.f, 0.f, 0.f};
    uint32_t blo[CPT] = {0u, 0u, 0u, 0u};    // spike bits t<32
    uint32_t bhi[CPT] = {0u, 0u, 0u, 0u};    // spike bits t>=32

#pragma unroll
    for (int t = 0; t < T_ - PF; ++t) {
        const int slot = t & (PF - 1);
        asm volatile("s_waitcnt vmcnt(7)" : "+v"(xs[slot]));
        const f32x4 xt = xs[slot];
        const f32x4* a = xv + (size_t)(t + PF) * RS;
        asm volatile("global_load_dwordx4 %0, %1, off" : "=v"(xs[slot]) : "v"(a));

#pragma unroll
        for (int c = 0; c < CPT; ++c) {
            const float t1 = mom * v[c];     // separately rounded, matches numpy
            const float t2 = lamb * u[c];
            v[c] = (t1 + xt[c]) - t2;
            u[c] = decay * u[c] + v[c];
            const bool sp = (u[c] >= 1.0f);
            if (t < 32) blo[c] |= ((uint32_t)sp) << t;
            else        bhi[c] |= ((uint32_t)sp) << (t - 32);
            u[c] = sp ? 0.0f : u[c];         // u*(1-s) is exactly this select
        }
    }

    asm volatile("s_waitcnt vmcnt(0)"
                 : "+v"(xs[0]), "+v"(xs[1]), "+v"(xs[2]), "+v"(xs[3]),
                   "+v"(xs[4]), "+v"(xs[5]), "+v"(xs[6]), "+v"(xs[7]));

#pragma unroll
    for (int t = T_ - PF; t < T_; ++t) {     // drain the ring, no more loads
        const f32x4 xt = xs[t & (PF - 1)];
#pragma unroll
        for (int c = 0; c < CPT; ++c) {
            const float t1 = mom * v[c];
            const float t2 = lamb * u[c];
            v[c] = (t1 + xt[c]) - t2;
            u[c] = decay * u[c] + v[c];
            const bool sp = (u[c] >= 1.0f);
            if (t < 32) blo[c] |= ((uint32_t)sp) << t;
            else        bhi[c] |= ((uint32_t)sp) << (t - 32);
            u[c] = sp ? 0.0f : u[c];
        }
    }

    // ---------------- Phase 2: pure-write burst -------------------------
#pragma unroll
    for (int t = 0; t < T_; ++t) {
        f32x4 o;
#pragma unroll
        for (int c = 0; c < CPT; ++c) {
            const uint32_t w = (t < 32) ? blo[c] : bhi[c];
            o[c] = ((w >> (t & 31)) & 1u) ? 1.0f : 0.0f;
        }
        __builtin_nontemporal_store(o, ov + (size_t)t * RS);
    }
}

extern "C" void kernel_launch(void* const* d_in, const int* in_sizes, int n_in,
                              void* d_out, int out_size, void* d_ws, size_t ws_size,
                              hipStream_t stream) {
    const float* x    = (const float*)d_in[0];
    const float* momp = (const float*)d_in[1];
    const float* lamb = (const float*)d_in[2];
    float* out = (float*)d_out;

    dim3 block(256);
    dim3 grid((N_ * D_ / CPT) / 256);   // 512 blocks, one thread per 4 chains
    hipLaunchKernelGGL(lif_fused, grid, block, 0, stream, x, momp, lamb, out);
}

// Round 5
// 236.473 us; speedup vs baseline: 1.0714x; 1.0526x over previous
//
#include <hip/hip_runtime.h>
#include <stdint.h>

// MomentumLIF: x[N,T,D] f32 -> spikes[N,T,D] f32 (0/1)
//   v_t = mom*v + x_t - lamb*u ; u_t = 0.5*u + v_t ; s = (u>=1); u *= (1-s)
//
// R13: back to the proven two-kernel split (best measured: R0, ~74 us kernel
// sum), with kernel A upgraded.
//   R4 post-mortem (HW lesson): mixed load/store vmcnt counting is UNSAFE --
//   loads and stores retire out-of-order relative to each other, so a
//   counted wait over a heterogeneous queue can unblock with the target
//   load still in flight (absmax 4.59). Counted vmcnt only over loads.
//   A: pure-read dwordx4 asm ring (8-deep, vmcnt(7), loads-only queue --
//      R3-verified correct), 4 chains/thread, bitpack spikes to ws (uint2
//      per chain). NEW: per-t s_barrier to stop wave drift across t-slabs
//      (DRAM row-thrash theory: dense copy sweeps monotonically at 6.3TB/s,
//      drifted strided walk measured 2.3-2.9 TB/s) + XCD-chunked swizzle so
//      each XCD walks 8 contiguous n-slabs.
//   B: R0-B verbatim (bit->float expand, fully contiguous nontemporal
//      float4 writes; structurally the 6.5 TB/s fill).
//   Arithmetic order identical to the absmax==0 kernels (contract off).

#define N_ 64
#define T_ 64
#define D_ 8192
#define PF 8    // asm load ring depth (float4 tiles in flight per thread)
#define CPT 4   // chains per thread in kernel A (one float4 of d)

typedef __attribute__((ext_vector_type(4))) float f32x4;

// ---------------- Kernel A: recurrence + bit-pack ----------------
__global__ __launch_bounds__(256) void lif_compute_pack(
    const float* __restrict__ x,
    const float* __restrict__ momp,
    const float* __restrict__ lambp,
    uint2* __restrict__ ws)
{
    // Match numpy f32 semantics exactly: no FMA contraction anywhere.
#pragma clang fp contract(off)
    float mom  = momp[0];
    float lamb = lambp[0];
    const float decay = 0.5f;   // 1 - 1/TAU, exact

    // Pin scalars to SGPRs; vmcnt arithmetic must see only our asm loads.
    asm volatile("" : "+s"(mom), "+s"(lamb));

    // XCD-chunked swizzle: hw bid b lands on XCD b%8; remap so XCD j owns
    // 64 consecutive logical blocks = 8 contiguous n-slabs (16 MB).
    // 512 = 8*64 exactly -> bijective.
    const int bid  = (int)blockIdx.x;
    const int lbid = (bid & 7) * 64 + (bid >> 3);

    const int g  = lbid * 256 + (int)threadIdx.x;  // 0 .. N*D/4 - 1
    const int n  = g >> 11;                  // g / (D_/CPT)
    const int dq = g & 2047;                 // float4 index within a row
    const size_t base = (size_t)n * (size_t)(T_ * D_) + ((size_t)dq << 2);

    const f32x4* __restrict__ xv = reinterpret_cast<const f32x4*>(x + base);
    const int RS = D_ / 4;                   // row stride in f32x4 units

    // Drain compiler-tracked vmem (momp/lambp loads) before our counting.
    asm volatile("s_waitcnt vmcnt(0)" ::: "memory");

    // Prologue: fill the 8-deep asm ring (queue = loads only).
    f32x4 xs[PF];
#pragma unroll
    for (int i = 0; i < PF; ++i) {
        const f32x4* a = xv + (size_t)i * RS;
        asm volatile("global_load_dwordx4 %0, %1, off" : "=v"(xs[i]) : "v"(a));
    }

    float u[CPT] = {0.f, 0.f, 0.f, 0.f};
    float v[CPT] = {0.f, 0.f, 0.f, 0.f};
    uint32_t blo[CPT] = {0u, 0u, 0u, 0u};    // spike bits t<32
    uint32_t bhi[CPT] = {0u, 0u, 0u, 0u};    // spike bits t>=32

#pragma unroll
    for (int t = 0; t < T_ - PF; ++t) {
        const int slot = t & (PF - 1);
        asm volatile("s_waitcnt vmcnt(7)" : "+v"(xs[slot]));
        const f32x4 xt = xs[slot];
        const f32x4* a = xv + (size_t)(t + PF) * RS;
        asm volatile("global_load_dwordx4 %0, %1, off" : "=v"(xs[slot]) : "v"(a));

#pragma unroll
        for (int c = 0; c < CPT; ++c) {
            const float t1 = mom * v[c];     // separately rounded, matches numpy
            const float t2 = lamb * u[c];
            v[c] = (t1 + xt[c]) - t2;
            u[c] = decay * u[c] + v[c];
            const bool sp = (u[c] >= 1.0f);
            if (t < 32) blo[c] |= ((uint32_t)sp) << t;
            else        bhi[c] |= ((uint32_t)sp) << (t - 32);
            u[c] = sp ? 0.0f : u[c];         // u*(1-s) is exactly this select
        }
        // Lockstep: keep the block's 8 waves on the same t-slab so the
        // chip-wide read window stays a few dense 2MB slices (anti-drift).
        __builtin_amdgcn_s_barrier();
    }

    asm volatile("s_waitcnt vmcnt(0)"
                 : "+v"(xs[0]), "+v"(xs[1]), "+v"(xs[2]), "+v"(xs[3]),
                   "+v"(xs[4]), "+v"(xs[5]), "+v"(xs[6]), "+v"(xs[7]));

#pragma unroll
    for (int t = T_ - PF; t < T_; ++t) {     // drain the ring, no more loads
        const f32x4 xt = xs[t & (PF - 1)];
#pragma unroll
        for (int c = 0; c < CPT; ++c) {
            const float t1 = mom * v[c];
            const float t2 = lamb * u[c];
            v[c] = (t1 + xt[c]) - t2;
            u[c] = decay * u[c] + v[c];
            const bool sp = (u[c] >= 1.0f);
            if (t < 32) blo[c] |= ((uint32_t)sp) << t;
            else        bhi[c] |= ((uint32_t)sp) << (t - 32);
            u[c] = sp ? 0.0f : u[c];
        }
    }

    // 4 chains -> 32 B contiguous; compiler merges to dwordx4 stores.
    const int chain = (n << 13) + (dq << 2); // n*D + dq*4
#pragma unroll
    for (int c = 0; c < CPT; ++c)
        ws[chain + c] = make_uint2(blo[c], bhi[c]);
}

// ---------------- Kernel B: bit -> float expand, pure-write ----------------
__global__ __launch_bounds__(256) void lif_expand(
    const uint2* __restrict__ ws,
    float* __restrict__ out)
{
    const int g = blockIdx.x * blockDim.x + threadIdx.x;  // one float4 of out
    const size_t e = (size_t)g << 2;          // element index, multiple of 4
    const int nt = (int)(e >> 13);            // n*T + t   (row = D elements)
    const int t  = nt & (T_ - 1);
    const int n  = nt >> 6;                   // / T_
    const int d  = (int)(e & (D_ - 1));
    const int chain = (n << 13) + d;          // n*D + d

    // 4 consecutive chains' packed words: 32 B contiguous, L2-resident
    // (ws is 4 MB, read 32x over the whole grid).
    const uint2 w0 = ws[chain + 0];
    const uint2 w1 = ws[chain + 1];
    const uint2 w2 = ws[chain + 2];
    const uint2 w3 = ws[chain + 3];

    const int  sh = t & 31;
    const bool hi = (t >= 32);

    f32x4 o;
    o.x = (((hi ? w0.y : w0.x) >> sh) & 1u) ? 1.0f : 0.0f;
    o.y = (((hi ? w1.y : w1.x) >> sh) & 1u) ? 1.0f : 0.0f;
    o.z = (((hi ? w2.y : w2.x) >> sh) & 1u) ? 1.0f : 0.0f;
    o.w = (((hi ? w3.y : w3.x) >> sh) & 1u) ? 1.0f : 0.0f;

    // Fully contiguous chip-wide write stream, 16 B/lane, nontemporal.
    __builtin_nontemporal_store(o, reinterpret_cast<f32x4*>(out) + g);
}

extern "C" void kernel_launch(void* const* d_in, const int* in_sizes, int n_in,
                              void* d_out, int out_size, void* d_ws, size_t ws_size,
                              hipStream_t stream) {
    const float* x    = (const float*)d_in[0];
    const float* momp = (const float*)d_in[1];
    const float* lamb = (const float*)d_in[2];
    float* out = (float*)d_out;
    uint2* ws  = (uint2*)d_ws;                // 524288 * 8 B = 4 MB

    // A: one thread per 4 chains.
    {
        dim3 block(256);
        dim3 grid((N_ * D_ / CPT) / 256);     // 512 blocks
        hipLaunchKernelGGL(lif_compute_pack, grid, block, 0, stream,
                           x, momp, lamb, ws);
    }
    // B: one thread per float4 of out.
    {
        dim3 block(256);
        dim3 grid((N_ * T_ * D_ / 4) / 256);  // 32768 blocks
        hipLaunchKernelGGL(lif_expand, grid, block, 0, stream, ws, out);
    }
}